// Round 2
// baseline (113.837 us; speedup 1.0000x reference)
//
#include <hip/hip_runtime.h>

// ViewLearner edge-MLP: out[e] = relu(concat(emb[src[e]],emb[dst[e]]) @ W1 + b1) @ W2 + b2
// R2: software-pipelined gather. Indices prefetched 2 iterations ahead, node rows
// 1 iteration ahead, so random-gather latency (L2/L3) overlaps MFMA + epilogue.

typedef __attribute__((ext_vector_type(8))) short short8;
typedef __attribute__((ext_vector_type(4))) float f32x4;

__device__ __forceinline__ unsigned short f2bf_rne(float f) {
    union { float f; unsigned u; } v;
    v.f = f;
    return (unsigned short)((v.u + 0x7FFFu + ((v.u >> 16) & 1u)) >> 16);
}

__global__ void cvt_to_bf16(const float* __restrict__ x,
                            unsigned short* __restrict__ y, int n4) {
    int i = blockIdx.x * blockDim.x + threadIdx.x;
    if (i >= n4) return;
    f32x4 v = ((const f32x4*)x)[i];
    ushort4 o;
    o.x = f2bf_rne(v[0]);
    o.y = f2bf_rne(v[1]);
    o.z = f2bf_rne(v[2]);
    o.w = f2bf_rne(v[3]);
    ((ushort4*)y)[i] = o;
}

#define W1T_STRIDE 136  // 128 + 8 shorts pad

struct Rows { short8 a0, a1, a2, a3; };

__device__ __forceinline__ Rows load_rows(const unsigned short* __restrict__ nodebf,
                                          int src, int dst, int ko) {
    Rows r;
    const unsigned short* rs = nodebf + (size_t)src * 64;
    const unsigned short* rd = nodebf + (size_t)dst * 64;
    r.a0 = *(const short8*)(rs + ko);
    r.a1 = *(const short8*)(rs + 32 + ko);
    r.a2 = *(const short8*)(rd + ko);
    r.a3 = *(const short8*)(rd + 32 + ko);
    return r;
}

__global__ __launch_bounds__(256, 3)
void edge_mlp(const int* __restrict__ eidx,
              const unsigned short* __restrict__ nodebf,
              const float* __restrict__ W1,
              const float* __restrict__ b1,
              const float* __restrict__ W2,
              const float* __restrict__ b2,
              float* __restrict__ out,
              int E, int ntiles) {
    __shared__ __align__(16) unsigned short w1t[64 * W1T_STRIDE];

    const int tid = threadIdx.x;

    // Stage W1^T (bf16) into LDS: w1t[n*W1T_STRIDE + k] = bf16(W1[k*64 + n]).
#pragma unroll
    for (int i = 0; i < 32; ++i) {
        int idx = tid + i * 256;
        int k = idx >> 6;
        int n = idx & 63;
        w1t[n * W1T_STRIDE + k] = f2bf_rne(W1[idx]);
    }
    __syncthreads();

    const int lane = tid & 63;
    const int wid = tid >> 6;
    const int c = lane & 15;     // A: edge-in-tile m; B/C: col
    const int quad = lane >> 4;  // 0..3
    const int ko = quad * 8;

    // B fragments pinned in VGPRs: bfrag[nt][kc] = W1[kc*32+quad*8+j][nt*16+c]
    short8 bfrag[4][4];
#pragma unroll
    for (int nt = 0; nt < 4; ++nt)
#pragma unroll
        for (int kc = 0; kc < 4; ++kc)
            bfrag[nt][kc] =
                *(const short8*)&w1t[(nt * 16 + c) * W1T_STRIDE + kc * 32 + quad * 8];

    float w2v[4], b1v[4];
#pragma unroll
    for (int nt = 0; nt < 4; ++nt) {
        w2v[nt] = W2[nt * 16 + c];
        b1v[nt] = b1[nt * 16 + c];
    }
    const float b2v = b2[0];

    const int stride = gridDim.x * 4;
    int t = blockIdx.x * 4 + wid;
    int tn = t + stride;

    // Pipeline prologue: idx(t) -> rows(t); idx(t+stride)
    int snxt = 0, dnxt = 0;
    Rows cur;
    if (t < ntiles) {
        int e = t * 16 + c;
        int ec = (e < E) ? e : (E - 1);
        int s = eidx[ec], d = eidx[E + ec];
        cur = load_rows(nodebf, s, d, ko);
        if (tn < ntiles) {
            int en = tn * 16 + c;
            int enc = (en < E) ? en : (E - 1);
            snxt = eidx[enc];
            dnxt = eidx[E + enc];
        }
    }

    for (; t < ntiles; t += stride, tn += stride) {
        const bool has_next = (tn < ntiles);
        Rows nxt;
        if (has_next) nxt = load_rows(nodebf, snxt, dnxt, ko);  // overlaps compute below

        int t2 = tn + stride;
        int s2 = 0, d2 = 0;
        if (t2 < ntiles) {
            int e2 = t2 * 16 + c;
            int e2c = (e2 < E) ? e2 : (E - 1);
            s2 = eidx[e2c];
            d2 = eidx[E + e2c];
        }

        f32x4 acc[4];
#pragma unroll
        for (int nt = 0; nt < 4; ++nt) acc[nt] = (f32x4){0.f, 0.f, 0.f, 0.f};
#pragma unroll
        for (int nt = 0; nt < 4; ++nt) {
            acc[nt] = __builtin_amdgcn_mfma_f32_16x16x32_bf16(cur.a0, bfrag[nt][0], acc[nt], 0, 0, 0);
            acc[nt] = __builtin_amdgcn_mfma_f32_16x16x32_bf16(cur.a1, bfrag[nt][1], acc[nt], 0, 0, 0);
            acc[nt] = __builtin_amdgcn_mfma_f32_16x16x32_bf16(cur.a2, bfrag[nt][2], acc[nt], 0, 0, 0);
            acc[nt] = __builtin_amdgcn_mfma_f32_16x16x32_bf16(cur.a3, bfrag[nt][3], acc[nt], 0, 0, 0);
        }

        // Epilogue: C layout col=lane&15 (=hid), row=quad*4+reg (=edge).
        float p[4];
#pragma unroll
        for (int r = 0; r < 4; ++r) p[r] = 0.f;
#pragma unroll
        for (int nt = 0; nt < 4; ++nt)
#pragma unroll
            for (int r = 0; r < 4; ++r) {
                float h = fmaxf(acc[nt][r] + b1v[nt], 0.f);
                p[r] = fmaf(h, w2v[nt], p[r]);
            }
#pragma unroll
        for (int m = 1; m < 16; m <<= 1)
#pragma unroll
            for (int r = 0; r < 4; ++r) p[r] += __shfl_xor(p[r], m, 16);

        if (c == 0) {
            int base = t * 16 + quad * 4;
            if (base + 3 < E) {
                f32x4 o = {p[0] + b2v, p[1] + b2v, p[2] + b2v, p[3] + b2v};
                *(f32x4*)(out + base) = o;
            } else {
#pragma unroll
                for (int r = 0; r < 4; ++r)
                    if (base + r < E) out[base + r] = p[r] + b2v;
            }
        }

        // Rotate pipeline registers.
        if (has_next) cur = nxt;
        snxt = s2;
        dnxt = d2;
    }
}

extern "C" void kernel_launch(void* const* d_in, const int* in_sizes, int n_in,
                              void* d_out, int out_size, void* d_ws, size_t ws_size,
                              hipStream_t stream) {
    const float* node = (const float*)d_in[0];
    const int* eidx = (const int*)d_in[1];
    const float* W1 = (const float*)d_in[2];
    const float* b1 = (const float*)d_in[3];
    const float* W2 = (const float*)d_in[4];
    const float* b2 = (const float*)d_in[5];
    float* out = (float*)d_out;

    const int node_elems = in_sizes[0];
    const int E = in_sizes[1] / 2;
    const int n4 = node_elems / 4;

    unsigned short* nodebf = (unsigned short*)d_ws;

    cvt_to_bf16<<<(n4 + 255) / 256, 256, 0, stream>>>(node, nodebf, n4);

    const int ntiles = (E + 15) / 16;
    edge_mlp<<<2048, 256, 0, stream>>>(eidx, nodebf, W1, b1, W2, b2, out, E, ntiles);
}

// Round 3
// 112.123 us; speedup vs baseline: 1.0153x; 1.0153x over previous
//
#include <hip/hip_runtime.h>

// ViewLearner edge-MLP: out[e] = relu(concat(emb[src[e]],emb[dst[e]]) @ W1 + b1) @ W2 + b2
// R3: copy-free 2-stage software pipeline. Loop unrolled x2; rowsA/rowsB have stable
// register homes (no rotate copies, no conditional loads). Gathers for tile t+1 issue
// before the MFMAs of tile t, overlapping L2/L3 gather latency with compute.

typedef __attribute__((ext_vector_type(8))) short short8;
typedef __attribute__((ext_vector_type(4))) float f32x4;

__device__ __forceinline__ unsigned short f2bf_rne(float f) {
    union { float f; unsigned u; } v;
    v.f = f;
    return (unsigned short)((v.u + 0x7FFFu + ((v.u >> 16) & 1u)) >> 16);
}

__global__ void cvt_to_bf16(const float* __restrict__ x,
                            unsigned short* __restrict__ y, int n4) {
    int i = blockIdx.x * blockDim.x + threadIdx.x;
    if (i >= n4) return;
    f32x4 v = ((const f32x4*)x)[i];
    ushort4 o;
    o.x = f2bf_rne(v[0]);
    o.y = f2bf_rne(v[1]);
    o.z = f2bf_rne(v[2]);
    o.w = f2bf_rne(v[3]);
    ((ushort4*)y)[i] = o;
}

#define W1T_STRIDE 136  // 128 + 8 shorts pad

struct Rows { short8 a0, a1, a2, a3; };

__device__ __forceinline__ Rows load_rows(const unsigned short* __restrict__ nodebf,
                                          int src, int dst, int ko) {
    Rows r;
    const unsigned short* rs = nodebf + (size_t)src * 64;
    const unsigned short* rd = nodebf + (size_t)dst * 64;
    r.a0 = *(const short8*)(rs + ko);
    r.a1 = *(const short8*)(rs + 32 + ko);
    r.a2 = *(const short8*)(rd + ko);
    r.a3 = *(const short8*)(rd + 32 + ko);
    return r;
}

// Unconditional, clamped index fetch (safe for t >= ntiles; results discarded).
__device__ __forceinline__ int2 fetch_idx(const int* __restrict__ eidx, int E,
                                          int t, int c) {
    int e = t * 16 + c;
    e = (e < E) ? e : (E - 1);
    int2 r;
    r.x = eidx[e];
    r.y = eidx[E + e];
    return r;
}

__device__ __forceinline__ void compute_tile(const Rows& rows,
                                             const short8 (&bfrag)[4][4],
                                             const float (&b1v)[4], const float (&w2v)[4],
                                             float b2v, int t, int ntiles, int E,
                                             int c, int quad,
                                             float* __restrict__ out) {
    if (t >= ntiles) return;  // wave-uniform guard

    f32x4 acc[4];
#pragma unroll
    for (int nt = 0; nt < 4; ++nt) acc[nt] = (f32x4){0.f, 0.f, 0.f, 0.f};
#pragma unroll
    for (int nt = 0; nt < 4; ++nt) {
        acc[nt] = __builtin_amdgcn_mfma_f32_16x16x32_bf16(rows.a0, bfrag[nt][0], acc[nt], 0, 0, 0);
        acc[nt] = __builtin_amdgcn_mfma_f32_16x16x32_bf16(rows.a1, bfrag[nt][1], acc[nt], 0, 0, 0);
        acc[nt] = __builtin_amdgcn_mfma_f32_16x16x32_bf16(rows.a2, bfrag[nt][2], acc[nt], 0, 0, 0);
        acc[nt] = __builtin_amdgcn_mfma_f32_16x16x32_bf16(rows.a3, bfrag[nt][3], acc[nt], 0, 0, 0);
    }

    // C layout: col=lane&15 (=hid low), row=quad*4+reg (=edge-in-tile).
    float p[4];
#pragma unroll
    for (int r = 0; r < 4; ++r) p[r] = 0.f;
#pragma unroll
    for (int nt = 0; nt < 4; ++nt)
#pragma unroll
        for (int r = 0; r < 4; ++r) {
            float h = fmaxf(acc[nt][r] + b1v[nt], 0.f);
            p[r] = fmaf(h, w2v[nt], p[r]);
        }
#pragma unroll
    for (int m = 1; m < 16; m <<= 1)
#pragma unroll
        for (int r = 0; r < 4; ++r) p[r] += __shfl_xor(p[r], m, 16);

    if (c == 0) {
        int base = t * 16 + quad * 4;
        if (base + 3 < E) {
            f32x4 o = {p[0] + b2v, p[1] + b2v, p[2] + b2v, p[3] + b2v};
            *(f32x4*)(out + base) = o;
        } else {
#pragma unroll
            for (int r = 0; r < 4; ++r)
                if (base + r < E) out[base + r] = p[r] + b2v;
        }
    }
}

__global__ __launch_bounds__(256, 3)
void edge_mlp(const int* __restrict__ eidx,
              const unsigned short* __restrict__ nodebf,
              const float* __restrict__ W1,
              const float* __restrict__ b1,
              const float* __restrict__ W2,
              const float* __restrict__ b2,
              float* __restrict__ out,
              int E, int ntiles) {
    __shared__ __align__(16) unsigned short w1t[64 * W1T_STRIDE];

    const int tid = threadIdx.x;

    // Stage W1^T (bf16) into LDS: w1t[n*W1T_STRIDE + k] = bf16(W1[k*64 + n]).
#pragma unroll
    for (int i = 0; i < 32; ++i) {
        int idx = tid + i * 256;
        int k = idx >> 6;
        int n = idx & 63;
        w1t[n * W1T_STRIDE + k] = f2bf_rne(W1[idx]);
    }
    __syncthreads();

    const int lane = tid & 63;
    const int wid = tid >> 6;
    const int c = lane & 15;
    const int quad = lane >> 4;
    const int ko = quad * 8;

    // B fragments pinned in VGPRs.
    short8 bfrag[4][4];
#pragma unroll
    for (int nt = 0; nt < 4; ++nt)
#pragma unroll
        for (int kc = 0; kc < 4; ++kc)
            bfrag[nt][kc] =
                *(const short8*)&w1t[(nt * 16 + c) * W1T_STRIDE + kc * 32 + quad * 8];

    float w2v[4], b1v[4];
#pragma unroll
    for (int nt = 0; nt < 4; ++nt) {
        w2v[nt] = W2[nt * 16 + c];
        b1v[nt] = b1[nt * 16 + c];
    }
    const float b2v = b2[0];

    // Each wave owns consecutive tile pairs (t, t+1), grid-strided by S.
    const int S = gridDim.x * 4 * 2;
    int t = (blockIdx.x * 4 + wid) * 2;

    // Prologue: indices+rows for tile t, indices for t+1.
    int2 iA = fetch_idx(eidx, E, t, c);
    Rows rowsA = load_rows(nodebf, iA.x, iA.y, ko);
    int2 iB = fetch_idx(eidx, E, t + 1, c);
    Rows rowsB;

    for (; t < ntiles; t += S) {
        // Phase A: start gather for t+1, prefetch indices for t+S, compute tile t.
        rowsB = load_rows(nodebf, iB.x, iB.y, ko);
        iA = fetch_idx(eidx, E, t + S, c);
        compute_tile(rowsA, bfrag, b1v, w2v, b2v, t, ntiles, E, c, quad, out);

        // Phase B: start gather for t+S, prefetch indices for t+S+1, compute tile t+1.
        rowsA = load_rows(nodebf, iA.x, iA.y, ko);
        iB = fetch_idx(eidx, E, t + S + 1, c);
        compute_tile(rowsB, bfrag, b1v, w2v, b2v, t + 1, ntiles, E, c, quad, out);
    }
}

extern "C" void kernel_launch(void* const* d_in, const int* in_sizes, int n_in,
                              void* d_out, int out_size, void* d_ws, size_t ws_size,
                              hipStream_t stream) {
    const float* node = (const float*)d_in[0];
    const int* eidx = (const int*)d_in[1];
    const float* W1 = (const float*)d_in[2];
    const float* b1 = (const float*)d_in[3];
    const float* W2 = (const float*)d_in[4];
    const float* b2 = (const float*)d_in[5];
    float* out = (float*)d_out;

    const int node_elems = in_sizes[0];
    const int E = in_sizes[1] / 2;
    const int n4 = node_elems / 4;

    unsigned short* nodebf = (unsigned short*)d_ws;

    cvt_to_bf16<<<(n4 + 255) / 256, 256, 0, stream>>>(node, nodebf, n4);

    const int ntiles = (E + 15) / 16;
    edge_mlp<<<1024, 256, 0, stream>>>(eidx, nodebf, W1, b1, W2, b2, out, E, ntiles);
}

// Round 4
// 103.128 us; speedup vs baseline: 1.1038x; 1.0872x over previous
//
#include <hip/hip_runtime.h>

// ViewLearner edge-MLP, restructured:
//   K1 (node_uv): UV[n] = [ x_n @ W1[0:64] + b1 | x_n @ W1[64:128] ]  (fp16, 12.8 MB in ws)
//       -- one small MFMA GEMM over nodes (sequential rows, no gather).
//   K2 (edge_out): out[e] = relu(UV[src][0:64] + UV[dst][64:128]) . W2 + b2
//       -- 192 FLOP/edge, 8 lanes per edge, pure gather+VALU, max TLP.

typedef __attribute__((ext_vector_type(8))) short short8;
typedef __attribute__((ext_vector_type(4))) float f32x4;
typedef __attribute__((ext_vector_type(8))) _Float16 half8;

__device__ __forceinline__ unsigned short f2bf_rne(float f) {
    union { float f; unsigned u; } v;
    v.f = f;
    return (unsigned short)((v.u + 0x7FFFu + ((v.u >> 16) & 1u)) >> 16);
}

#define W1T_K 72       // 64 + 8 shorts pad
#define CT_STRIDE 136  // 128 + 8 halfs pad

// ---- K1: per-node U|V table via 16x16x32 bf16 MFMA --------------------------
__global__ __launch_bounds__(256)
void node_uv(const float* __restrict__ X,
             const float* __restrict__ W1,
             const float* __restrict__ b1,
             _Float16* __restrict__ UV,
             int nnodes, int ntiles) {
    // B matrix [k<64][j'<128]: j'<64 -> W1[k][j'] (U), j'>=64 -> W1[64+k][j'-64] (V)
    __shared__ __align__(16) unsigned short w1t[128 * W1T_K];
    __shared__ __align__(16) _Float16 cbuf[4][16 * CT_STRIDE];

    const int tid = threadIdx.x;
#pragma unroll
    for (int i = 0; i < 32; ++i) {
        int idx = tid + i * 256;  // 8192 = 128*64 elements of W1, coalesced read
        int r = idx >> 6;         // W1 row (input dim) 0..127
        int col = idx & 63;       // W1 col (hidden)    0..63
        int k = r & 63;
        int jp = col + (r & 64);  // r>=64 -> V half (cols 64..127)
        w1t[jp * W1T_K + k] = f2bf_rne(W1[idx]);
    }
    __syncthreads();

    const int lane = tid & 63;
    const int wid = tid >> 6;
    const int c = lane & 15;
    const int quad = lane >> 4;

    const int t = blockIdx.x * 4 + wid;
    if (t >= ntiles) return;  // wave-uniform

    // B frags: bfrag[nt][kc] = B[k = kc*32+quad*8+j][col = nt*16+c]
    short8 bfrag[8][2];
#pragma unroll
    for (int nt = 0; nt < 8; ++nt)
#pragma unroll
        for (int kc = 0; kc < 2; ++kc)
            bfrag[nt][kc] =
                *(const short8*)&w1t[(nt * 16 + c) * W1T_K + kc * 32 + quad * 8];

    float b1v[8];
#pragma unroll
    for (int nt = 0; nt < 8; ++nt)
        b1v[nt] = (nt < 4) ? b1[nt * 16 + c] : 0.f;  // fold b1 into U half only

    // A row (node) loads: sequential rows, coalesced; convert fp32 -> bf16.
    int n = t * 16 + c;
    n = (n < nnodes) ? n : (nnodes - 1);
    const float* xr = X + (size_t)n * 64 + quad * 8;
    f32x4 x0a = *(const f32x4*)(xr);
    f32x4 x0b = *(const f32x4*)(xr + 4);
    f32x4 x1a = *(const f32x4*)(xr + 32);
    f32x4 x1b = *(const f32x4*)(xr + 36);
    short8 a0, a1;
#pragma unroll
    for (int i = 0; i < 4; ++i) {
        a0[i] = (short)f2bf_rne(x0a[i]);
        a0[4 + i] = (short)f2bf_rne(x0b[i]);
        a1[i] = (short)f2bf_rne(x1a[i]);
        a1[4 + i] = (short)f2bf_rne(x1b[i]);
    }

    f32x4 acc[8];
#pragma unroll
    for (int nt = 0; nt < 8; ++nt) acc[nt] = (f32x4){0.f, 0.f, 0.f, 0.f};
#pragma unroll
    for (int nt = 0; nt < 8; ++nt) {
        acc[nt] = __builtin_amdgcn_mfma_f32_16x16x32_bf16(a0, bfrag[nt][0], acc[nt], 0, 0, 0);
        acc[nt] = __builtin_amdgcn_mfma_f32_16x16x32_bf16(a1, bfrag[nt][1], acc[nt], 0, 0, 0);
    }

    // C layout: col j' = nt*16+c, row = quad*4+r. Repack via per-wave LDS region
    // to fp16, then coalesced 4 KB contiguous store (UV tile rows are contiguous).
    _Float16* cb = cbuf[wid];
#pragma unroll
    for (int nt = 0; nt < 8; ++nt)
#pragma unroll
        for (int r = 0; r < 4; ++r)
            cb[(quad * 4 + r) * CT_STRIDE + nt * 16 + c] =
                (_Float16)(acc[nt][r] + b1v[nt]);

    __builtin_amdgcn_s_waitcnt(0);  // drain ds_writes before cross-lane ds_read

    // lane l copies 32 halfs: global flat g = l*32 + i -> row g/128, col g%128
    const _Float16* rp = &cb[(lane >> 2) * CT_STRIDE + (lane & 3) * 32];
    const f32x4* s4 = (const f32x4*)rp;
    f32x4* dst = (f32x4*)(UV + (size_t)t * 2048 + lane * 32);
    dst[0] = s4[0];
    dst[1] = s4[1];
    dst[2] = s4[2];
    dst[3] = s4[3];
}

// ---- K2: per-edge gather + relu + dot(W2) -----------------------------------
__global__ __launch_bounds__(256)
void edge_out(const int* __restrict__ eidx,
              const _Float16* __restrict__ UV,
              const float* __restrict__ W2,
              const float* __restrict__ b2,
              float* __restrict__ out, int E) {
    int tid = blockIdx.x * 256 + threadIdx.x;
    int e = tid >> 3;       // 8 lanes per edge
    int j = tid & 7;        // hidden chunk [j*8, j*8+8)
    if (e >= E) return;

    int src = eidx[e];
    int dst = eidx[E + e];

    half8 u = *(const half8*)(UV + (size_t)src * 128 + j * 8);
    half8 v = *(const half8*)(UV + (size_t)dst * 128 + 64 + j * 8);
    f32x4 w2a = *(const f32x4*)(W2 + j * 8);
    f32x4 w2b = *(const f32x4*)(W2 + j * 8 + 4);

    float acc = 0.f;
#pragma unroll
    for (int i = 0; i < 4; ++i) {
        float h0 = fmaxf((float)u[i] + (float)v[i], 0.f);
        float h1 = fmaxf((float)u[4 + i] + (float)v[4 + i], 0.f);
        acc = fmaf(h0, w2a[i], acc);
        acc = fmaf(h1, w2b[i], acc);
    }
    acc += __shfl_xor(acc, 1, 8);
    acc += __shfl_xor(acc, 2, 8);
    acc += __shfl_xor(acc, 4, 8);
    if (j == 0) out[e] = acc + b2[0];
}

extern "C" void kernel_launch(void* const* d_in, const int* in_sizes, int n_in,
                              void* d_out, int out_size, void* d_ws, size_t ws_size,
                              hipStream_t stream) {
    const float* X = (const float*)d_in[0];
    const int* eidx = (const int*)d_in[1];
    const float* W1 = (const float*)d_in[2];
    const float* b1 = (const float*)d_in[3];
    const float* W2 = (const float*)d_in[4];
    const float* b2 = (const float*)d_in[5];
    float* out = (float*)d_out;

    const int nnodes = in_sizes[0] / 64;
    const int E = in_sizes[1] / 2;

    _Float16* UV = (_Float16*)d_ws;  // [nnodes_padded][128] fp16, ~12.8 MB

    const int ntiles = (nnodes + 15) / 16;
    node_uv<<<(ntiles + 3) / 4, 256, 0, stream>>>(X, W1, b1, UV, nnodes, ntiles);

    const int nthreads = E * 8;
    edge_out<<<(nthreads + 255) / 256, 256, 0, stream>>>(eidx, UV, W2, b2, out, E);
}